// Round 4
// baseline (367.669 us; speedup 1.0000x reference)
//
#include <hip/hip_runtime.h>
#include <hip/hip_bf16.h>

#define T_LEN 1024
#define D_DIM 64
#define BATCH 32

// ---------------------------------------------------------------------------
// Kernel 1: pairwise Euclidean distance, GEMM-trick.
// 128x128 tile, 256 threads, 8x8 micro-tile per thread (split 4+4 rows/cols
// 64 apart: B-reads lane-contiguous conflict-free, A-broadcast 2-way=free).
// 16 ds_read_b128 per 256 FMA (was 12 per 128) -> LDS-issue pressure halved.
// Per-element k-accumulation order identical to previous kernels ->
// bit-identical cost matrix.
// ---------------------------------------------------------------------------
#define BM 128
#define BN 128

__global__ __launch_bounds__(256, 2) void cost_kernel(const float* __restrict__ pred,
                                                      const float* __restrict__ targ,
                                                      float* __restrict__ cost) {
    const int b = blockIdx.z;
    const float* P = pred + (size_t)b * T_LEN * D_DIM;
    const float* Tg = targ + (size_t)b * T_LEN * D_DIM;
    float* C = cost + (size_t)b * T_LEN * T_LEN;
    const int row0 = blockIdx.y * BM;
    const int col0 = blockIdx.x * BN;

    __shared__ __align__(16) float ps[BM][D_DIM + 4];   // 128 x 68 row-major
    __shared__ __align__(16) float ts[D_DIM][BN + 4];   // 64 x 132 k-major
    __shared__ float p2[BM], t2[BN];

    const int tid = threadIdx.x;

    // stage pred: 128 rows x 16 float4 chunks = 2048 -> 8 iters
#pragma unroll
    for (int it = 0; it < 8; ++it) {
        int f = tid + 256 * it;
        int row = f >> 4;
        int kc = f & 15;
        float4 v = *(const float4*)(P + (size_t)(row0 + row) * D_DIM + 4 * kc);
        *(float4*)&ps[row][4 * kc] = v;
    }
    // stage targ transposed: 128 cols x 16 chunks = 2048 -> 8 iters
#pragma unroll
    for (int it = 0; it < 8; ++it) {
        int f = tid + 256 * it;
        int col = f >> 4;
        int kc = f & 15;
        float4 w = *(const float4*)(Tg + (size_t)(col0 + col) * D_DIM + 4 * kc);
        ts[4 * kc + 0][col] = w.x;
        ts[4 * kc + 1][col] = w.y;
        ts[4 * kc + 2][col] = w.z;
        ts[4 * kc + 3][col] = w.w;
    }
    __syncthreads();

    // squared norms, same sequential-k order as before
    if (tid < 128) {
        float s = 0.0f;
        const float4* pr = (const float4*)&ps[tid][0];
#pragma unroll
        for (int q = 0; q < 16; ++q) {
            float4 v = pr[q];
            s += v.x * v.x; s += v.y * v.y; s += v.z * v.z; s += v.w * v.w;
        }
        p2[tid] = s;
    } else {
        int c = tid - 128;
        float s = 0.0f;
#pragma unroll
        for (int k = 0; k < 64; ++k) { float x = ts[k][c]; s += x * x; }
        t2[c] = s;
    }
    __syncthreads();

    // 8x8 micro-tile: rows {4ty..4ty+3, 64+4ty..}, cols {4tx.., 64+4tx..}
    const int tx = tid & 15;             // 16 col-groups
    const int ty = tid >> 4;             // 16 row-groups
    const int cl = 4 * tx;               // low col base
    const int ch = 64 + 4 * tx;          // high col base

    float acc[8][8];
#pragma unroll
    for (int i = 0; i < 8; ++i)
#pragma unroll
        for (int j = 0; j < 8; ++j) acc[i][j] = 0.0f;

#pragma unroll
    for (int k4 = 0; k4 < 16; ++k4) {
        float4 bl[4], bh[4];
#pragma unroll
        for (int kk = 0; kk < 4; ++kk) {
            bl[kk] = *(const float4*)&ts[4 * k4 + kk][cl];
            bh[kk] = *(const float4*)&ts[4 * k4 + kk][ch];
        }
#pragma unroll
        for (int ih = 0; ih < 2; ++ih) {
#pragma unroll
            for (int i = 0; i < 4; ++i) {
                const int rr = (ih ? 64 + 4 * ty : 4 * ty) + i;
                float4 av = *(const float4*)&ps[rr][4 * k4];
                const float a4[4] = {av.x, av.y, av.z, av.w};
                float* A = acc[4 * ih + i];
#pragma unroll
                for (int kk = 0; kk < 4; ++kk) {
                    const float* blp = (const float*)&bl[kk];
                    const float* bhp = (const float*)&bh[kk];
                    const float ak = a4[kk];
#pragma unroll
                    for (int j = 0; j < 4; ++j) {
                        A[j]     += ak * blp[j];
                        A[4 + j] += ak * bhp[j];
                    }
                }
            }
        }
    }

    float4 tlo = *(const float4*)&t2[cl];
    float4 thi = *(const float4*)&t2[ch];
    const float* tl = (const float*)&tlo;
    const float* th = (const float*)&thi;
#pragma unroll
    for (int ih = 0; ih < 2; ++ih) {
#pragma unroll
        for (int i = 0; i < 4; ++i) {
            const int rr = (ih ? 64 + 4 * ty : 4 * ty) + i;
            const float pa = p2[rr];
            float* A = acc[4 * ih + i];
            float4 o1, o2;
            o1.x = sqrtf(fmaxf(pa + tl[0] - 2.0f * A[0], 1e-12f));
            o1.y = sqrtf(fmaxf(pa + tl[1] - 2.0f * A[1], 1e-12f));
            o1.z = sqrtf(fmaxf(pa + tl[2] - 2.0f * A[2], 1e-12f));
            o1.w = sqrtf(fmaxf(pa + tl[3] - 2.0f * A[3], 1e-12f));
            o2.x = sqrtf(fmaxf(pa + th[0] - 2.0f * A[4], 1e-12f));
            o2.y = sqrtf(fmaxf(pa + th[1] - 2.0f * A[5], 1e-12f));
            o2.z = sqrtf(fmaxf(pa + th[2] - 2.0f * A[6], 1e-12f));
            o2.w = sqrtf(fmaxf(pa + th[3] - 2.0f * A[7], 1e-12f));
            float* Crow = C + (size_t)(row0 + rr) * T_LEN + col0;
            *(float4*)(Crow + cl) = o1;
            *(float4*)(Crow + ch) = o2;
        }
    }
}

// ---------------------------------------------------------------------------
// Kernel 2: Frechet DP, one wave per batch, time-skewed pipeline.
// 8-deep register pipeline as 32 INDIVIDUALLY-NAMED float4 vars (no array
// -> nothing address-taken -> SROA keeps them in VGPRs; rounds 0/3 showed
// VGPR=88 = array spilled to scratch, ~250cy exposed per step). Inline-asm
// global_load_dwordx4 (invisible to SIInsertWaitcnts -> no auto vmcnt(0)
// drain), consumed under counted s_waitcnt vmcnt(28) + sched_barrier(0).
// Recurrence: max(c,min(min(up,left),diag)) == med3(left, c, max(c,min(up,diag)))
// -> 16 dependent med3 on the chain, g-terms off-chain (validated: absmax 0).
// ---------------------------------------------------------------------------
#define PD 8

#define DP_LOAD4(D0, D1, D2, D3, SRC)                                         \
    asm volatile("global_load_dwordx4 %0, %4, off\n\t"                        \
                 "global_load_dwordx4 %1, %4, off offset:16\n\t"              \
                 "global_load_dwordx4 %2, %4, off offset:32\n\t"              \
                 "global_load_dwordx4 %3, %4, off offset:48"                  \
                 : "=&v"(D0), "=&v"(D1), "=&v"(D2), "=&v"(D3)                 \
                 : "v"(SRC))

__global__ __launch_bounds__(64, 1) void dp_kernel(const float* __restrict__ cost,
                                                   float* __restrict__ out) {
    const int b = blockIdx.x;
    const int t = threadIdx.x;  // lane 0..63
    const float INF = __builtin_inff();
    const float* C = cost + (size_t)b * T_LEN * T_LEN + 16 * t;

    float prev[16];
#pragma unroll
    for (int j = 0; j < 16; ++j) prev[j] = INF;
    float right_out = INF;
    float diag_feed = INF;

    // 8 pipeline slots, 4 float4 each — all individually named.
    float4 A0, A1, A2, A3, B0, B1, B2, B3, C0_, C1_, C2_, C3_, D0_, D1_, D2_, D3_;
    float4 E0, E1, E2, E3, F0, F1, F2, F3, G0, G1, G2, G3, H0, H1, H2, H3;

#define DP_PROLOG(D, P0, P1, P2, P3)                                          \
    {                                                                         \
        int r = (D) - t; r = r < 0 ? 0 : r;                                   \
        const float* src = C + (size_t)r * T_LEN;                             \
        DP_LOAD4(P0, P1, P2, P3, src);                                        \
    }
    DP_PROLOG(0, A0, A1, A2, A3)
    DP_PROLOG(1, B0, B1, B2, B3)
    DP_PROLOG(2, C0_, C1_, C2_, C3_)
    DP_PROLOG(3, D0_, D1_, D2_, D3_)
    DP_PROLOG(4, E0, E1, E2, E3)
    DP_PROLOG(5, F0, F1, F2, F3)
    DP_PROLOG(6, G0, G1, G2, G3)
    DP_PROLOG(7, H0, H1, H2, H3)
#undef DP_PROLOG

    const int S = T_LEN + 63;                 // 1087 real steps
    const int NCH = (S + PD - 1) / PD;        // 136 chunks -> 1088 steps (tail guarded)
    int s = 0;

#define DP_STEP(P0, P1, P2, P3)                                               \
    {                                                                         \
        float inc = __shfl_up(right_out, 1, 64);                              \
        asm volatile("s_waitcnt vmcnt(28)" ::: "memory");                     \
        __builtin_amdgcn_sched_barrier(0);                                    \
        const int r = s - t;                                                  \
        float left = inc, diag = diag_feed;                                   \
        diag_feed = inc;                                                      \
        if (t == 0) { left = (r == 0) ? -INF : INF; diag = INF; }             \
        if (r >= 0 && r < T_LEN) {                                            \
            float cq[16] = {P0.x, P0.y, P0.z, P0.w, P1.x, P1.y, P1.z, P1.w,   \
                            P2.x, P2.y, P2.z, P2.w, P3.x, P3.y, P3.z, P3.w};  \
            float g[16];                                                      \
            g[0] = fmaxf(cq[0], fminf(prev[0], diag));                        \
            _Pragma("unroll")                                                 \
            for (int j = 1; j < 16; ++j)                                      \
                g[j] = fmaxf(cq[j], fminf(prev[j], prev[j - 1]));             \
            float v = left;                                                   \
            _Pragma("unroll")                                                 \
            for (int j = 0; j < 16; ++j) {                                    \
                v = __builtin_amdgcn_fmed3f(v, cq[j], g[j]);                  \
                prev[j] = v;                                                  \
            }                                                                 \
            right_out = v;                                                    \
        }                                                                     \
        __builtin_amdgcn_sched_barrier(0);                                    \
        {                                                                     \
            int rn = s + PD - t;                                              \
            rn = rn < 0 ? 0 : (rn > T_LEN - 1 ? T_LEN - 1 : rn);              \
            const float* src = C + (size_t)rn * T_LEN;                        \
            DP_LOAD4(P0, P1, P2, P3, src);                                    \
        }                                                                     \
        ++s;                                                                  \
    }

    for (int chunk = 0; chunk < NCH; ++chunk) {
        DP_STEP(A0, A1, A2, A3)
        DP_STEP(B0, B1, B2, B3)
        DP_STEP(C0_, C1_, C2_, C3_)
        DP_STEP(D0_, D1_, D2_, D3_)
        DP_STEP(E0, E1, E2, E3)
        DP_STEP(F0, F1, F2, F3)
        DP_STEP(G0, G1, G2, G3)
        DP_STEP(H0, H1, H2, H3)
    }
#undef DP_STEP

    asm volatile("s_waitcnt vmcnt(0)" ::: "memory");
    if (t == 63) atomicAdd(out, prev[15] * (1.0f / (float)BATCH));
}

// ---------------------------------------------------------------------------
// Fallback: fused DP computing distances on the fly (only if ws can't hold
// one 4 MB cost matrix). Unchanged.
// ---------------------------------------------------------------------------
__global__ __launch_bounds__(64) void dp_fused_kernel(const float* __restrict__ pred,
                                                      const float* __restrict__ targ,
                                                      float* __restrict__ out) {
    const int b = blockIdx.x;
    const int t = threadIdx.x;
    const float INF = __builtin_inff();
    const float* P = pred + (size_t)b * T_LEN * D_DIM;
    const float* T = targ + (size_t)b * T_LEN * D_DIM + (size_t)(16 * t) * D_DIM;

    float prev[16];
#pragma unroll
    for (int j = 0; j < 16; ++j) prev[j] = INF;
    float right_out = INF;
    float diag_feed = INF;

    for (int s = 0; s < T_LEN + 63; s++) {
        int r = s - t;
        float inc = __shfl_up(right_out, 1, 64);
        float left = inc, diag = diag_feed;
        diag_feed = inc;
        if (t == 0) { left = (r == 0) ? -INF : INF; diag = INF; }
        if (r >= 0 && r < T_LEN) {
            float4 pr[16];
            const float4* pp = (const float4*)(P + (size_t)r * D_DIM);
#pragma unroll
            for (int q = 0; q < 16; q++) pr[q] = pp[q];
#pragma unroll
            for (int j = 0; j < 16; j++) {
                const float4* tp = (const float4*)(T + (size_t)j * D_DIM);
                float acc = 0.0f;
#pragma unroll
                for (int q = 0; q < 16; q++) {
                    float4 tv = tp[q];
                    float dx = pr[q].x - tv.x; acc += dx * dx;
                    float dy = pr[q].y - tv.y; acc += dy * dy;
                    float dz = pr[q].z - tv.z; acc += dz * dz;
                    float dw = pr[q].w - tv.w; acc += dw * dw;
                }
                float c = sqrtf(fmaxf(acc, 1e-12f));
                float up = prev[j];
                float v = fmaxf(c, fminf(fminf(up, diag), left));
                diag = up; left = v; prev[j] = v;
            }
            right_out = left;
        }
    }
    if (t == 63) atomicAdd(out, prev[15] * (1.0f / (float)BATCH));
}

extern "C" void kernel_launch(void* const* d_in, const int* in_sizes, int n_in,
                              void* d_out, int out_size, void* d_ws, size_t ws_size,
                              hipStream_t stream) {
    const float* pred = (const float*)d_in[0];
    const float* targ = (const float*)d_in[1];
    float* out = (float*)d_out;

    hipMemsetAsync(out, 0, sizeof(float) * out_size, stream);

    const size_t per_batch = (size_t)T_LEN * T_LEN * sizeof(float);  // 4 MB
    int bpg = (int)(ws_size / per_batch);
    if (bpg > BATCH) bpg = BATCH;

    if (bpg >= 1) {
        float* cost = (float*)d_ws;
        for (int g0 = 0; g0 < BATCH; g0 += bpg) {
            int gb = (BATCH - g0) < bpg ? (BATCH - g0) : bpg;
            dim3 grid(T_LEN / BN, T_LEN / BM, gb);
            cost_kernel<<<grid, 256, 0, stream>>>(pred + (size_t)g0 * T_LEN * D_DIM,
                                                  targ + (size_t)g0 * T_LEN * D_DIM,
                                                  cost);
            dp_kernel<<<gb, 64, 0, stream>>>(cost, out);
        }
    } else {
        dp_fused_kernel<<<BATCH, 64, 0, stream>>>(pred, targ, out);
    }
}